// Round 19
// baseline (122.560 us; speedup 1.0000x reference)
//
#include <hip/hip_runtime.h>

// ---------------------------------------------------------------------------
// PyramidNSMLayer: 4-level anchor decode + top-4000 selection + greedy NMS.
//
// Pipeline (all on `stream`, graph-capturable, deterministic):
//   1. hist_kernel:    coalesced float4 stream, per-LEVEL block partition,
//                      period-3 score extract, LDS 8192-bin hist -> partials,
//                      dense scores[] sidecar (if ws allows)
//   2. reduce_kernel:  column-sum partials -> hist; zeroes rankArr/binCount
//   3. select_kernel:  parallel suffix-scan -> binStart[], B = LARGEST bin
//                      with suffix >= 4000
//   4. compact:        per-bin scatter, binCount 1 cacheline/bin
//   5. rank_kernel:    rank-by-counting exact sort (keys distinct), 2D-split;
//                      fused scatter (contribution count in bit 20; last
//                      contributor writes sorted[rank])
//   6. decode_kernel:  decode top-4000 ranks into boxes + supinit bitmask
//   7. iou_kernel:     upper-triangle 4000 x 4096 bitmask, 4 col-words/wave
//   8. greedy_kernel:  8 waves / 1 CU decoupled ring (R16/R18-proven).
//                      NEW: prefetcher waves also EXTRACT the chunk's diag
//                      slice (buf[lane*64+c], 64-way-conflicted -- but on
//                      the slack-rich prefetcher, not the scan) into a 2KB
//                      LDS array; the scan's per-pick mask update becomes a
//                      pure shfl of a register slice (~90cy/pick vs R18's
//                      ~150cy uniform-LDS-read chain).
// ---------------------------------------------------------------------------

namespace {

constexpr int kNTot = 3133440;   // total anchors across levels
constexpr int kB1 = 2359296;     // 512*512*9
constexpr int kB2 = 2949120;     // + 256*256*9
constexpr int kB3 = 3096576;     // + 128*128*9
constexpr int kNBins = 8192;
constexpr int kNParts = 256;     // histogram partial blocks
constexpr int kCap = 8192;       // candidate buffer capacity
constexpr int kTopK = 4000;
constexpr int kNPad = 4096;      // padded candidate count for 64-bit words
constexpr int kNRois = 300;
constexpr int kChunk = 64;       // greedy scan chunk (ranks per slot) == 1 word
constexpr int kNChunks = (kTopK + kChunk - 1) / kChunk;  // 63
constexpr int kNSlots = 4;       // LDS ring slots (32KB each)
constexpr int kNPref = 7;        // prefetcher waves (1-deep each, decoupled)
constexpr int kJChunk = 2048;    // rank j-chunk (16KB LDS)
constexpr int kITile = 256;      // rank i-tile (threads per block)
constexpr int kBCS = 16;         // binCount stride (u32) = 1 cacheline/bin
constexpr unsigned kDoneInc = 1u << 20;  // rank contribution-count increment

// float4-stream geometry (x inputs, layout (h,w,9,6) == linear float idx 6a)
constexpr int kF4L[4] = {3538944, 884736, 221184, 55296};  // per-level f4 count
constexpr int kLvlB0[5] = {0, 193, 241, 253, 256};         // block partition
constexpr int kLvlAB[4] = {0, kB1, kB2, kB3};

struct LevelPick { const float* x; unsigned local; };

__device__ __forceinline__ LevelPick pick_level(unsigned g, const float* x1, const float* x2,
                                                const float* x3, const float* x4) {
  LevelPick p;
  if (g < (unsigned)kB1)      { p.x = x1; p.local = g; }
  else if (g < (unsigned)kB2) { p.x = x2; p.local = g - kB1; }
  else if (g < (unsigned)kB3) { p.x = x3; p.local = g - kB2; }
  else                        { p.x = x4; p.local = g - kB3; }
  return p;
}

__device__ __forceinline__ int score_bin(float s) {
  int b = (int)(s * (float)kNBins);
  return min(max(b, 0), kNBins - 1);
}

// Strided fallback: 4 consecutive anchors' scores via aligned float4s.
__device__ __forceinline__ void load_scores4(const float* x, unsigned local0, float s[4]) {
  const float4* p = (const float4*)(x + (size_t)local0 * 6);
  float4 q0 = p[0], q1 = p[1], q3 = p[3], q4 = p[4];
  s[0] = q0.x; s[1] = q1.z; s[2] = q3.x; s[3] = q4.z;
}

// Coalesced stream pass, blocks statically partitioned across levels.
__global__ __launch_bounds__(1024) void hist_kernel(
    const float4* __restrict__ x1, const float4* __restrict__ x2,
    const float4* __restrict__ x3, const float4* __restrict__ x4,
    unsigned* __restrict__ part, float* __restrict__ scores) {
  __shared__ unsigned h[kNBins];
  for (int i = threadIdx.x; i < kNBins; i += 1024) h[i] = 0;
  __syncthreads();
  const int bid = blockIdx.x;
  int lvl = (bid < kLvlB0[1]) ? 0 : (bid < kLvlB0[2]) ? 1 : (bid < kLvlB0[3]) ? 2 : 3;
  const float4* x = (lvl == 0) ? x1 : (lvl == 1) ? x2 : (lvl == 2) ? x3 : x4;
  const int nf4 = kF4L[lvl];
  const int abase = kLvlAB[lvl];
  const int bloc = bid - kLvlB0[lvl];
  const int nblk = kLvlB0[lvl + 1] - kLvlB0[lvl];
  for (int q = bloc * 1024 + threadIdx.x; q < nf4; q += nblk * 1024) {
    float4 v = x[q];
    int qd = q / 3;
    int r = q - qd * 3;
    if (r != 2) {
      float s = (r == 0) ? v.x : v.z;
      atomicAdd(&h[score_bin(s)], 1u);
      if (scores) scores[abase + 2 * qd + r] = s;
    }
  }
  __syncthreads();
  for (int i = threadIdx.x; i < kNBins; i += 1024)
    part[blockIdx.x * kNBins + i] = h[i];
}

// hist[b] = sum over partials; also zeroes rankArr and binCount (replaces
// the memset dispatch; runs before their users in the stream).
__global__ void reduce_kernel(const unsigned* __restrict__ part, unsigned* __restrict__ hist,
                              unsigned* __restrict__ rankArr, unsigned* __restrict__ binCount) {
  int b = blockIdx.x * 256 + threadIdx.x;
  unsigned t0 = 0, t1 = 0, t2 = 0, t3 = 0;
  for (int p = 0; p < kNParts; p += 4) {
    t0 += part[(size_t)(p + 0) * kNBins + b];
    t1 += part[(size_t)(p + 1) * kNBins + b];
    t2 += part[(size_t)(p + 2) * kNBins + b];
    t3 += part[(size_t)(p + 3) * kNBins + b];
  }
  hist[b] = t0 + t1 + t2 + t3;
  rankArr[b] = 0;
  #pragma unroll
  for (int k = 0; k < kBCS; ++k) binCount[(size_t)b * kBCS + k] = 0;
}

// 1 block, 1024 threads. Parallel suffix scan of hist -> binStart[b] =
// #candidates in bins > b. B = LARGEST bin with suffix >= topk (atomicMax).
__global__ __launch_bounds__(1024) void select_kernel(
    const unsigned* __restrict__ hist, unsigned* __restrict__ sel,
    unsigned* __restrict__ counter, unsigned* __restrict__ binStart) {
  __shared__ unsigned wtot[16];
  __shared__ unsigned maxB;
  const int t = threadIdx.x;
  const int lane = t & 63;
  const int wv = t >> 6;
  if (t == 0) maxB = 0u;
  unsigned h[8];
  unsigned s = 0;
  #pragma unroll
  for (int i = 0; i < 8; ++i) { h[i] = hist[t * 8 + i]; s += h[i]; }
  unsigned p = s;
  #pragma unroll
  for (int off = 1; off < 64; off <<= 1) {
    unsigned n = __shfl_up(p, off);
    if (lane >= off) p += n;
  }
  if (lane == 63) wtot[wv] = p;
  __syncthreads();
  if (wv == 0 && lane < 16) {
    unsigned wp = wtot[lane];
    #pragma unroll
    for (int off = 1; off < 16; off <<= 1) {
      unsigned n = __shfl_up(wp, off);
      if (lane >= off) wp += n;
    }
    wtot[lane] = wp;  // inclusive across waves
  }
  __syncthreads();
  const unsigned total = wtot[15];
  const unsigned Pincl = p + (wv > 0 ? wtot[wv - 1] : 0u);
  const unsigned T = total - Pincl;  // sum over threads above t
  unsigned bs[8];
  bs[7] = T;
  #pragma unroll
  for (int i = 6; i >= 0; --i) bs[i] = bs[i + 1] + h[i + 1];
  #pragma unroll
  for (int i = 0; i < 8; ++i) binStart[t * 8 + i] = bs[i];
  unsigned cand = 0;
  #pragma unroll
  for (int i = 0; i < 8; ++i)            // ascending: ends at LARGEST
    if (bs[i] + h[i] >= (unsigned)kTopK) cand = (unsigned)(t * 8 + i);
  atomicMax(&maxB, cand);
  __syncthreads();
  const unsigned B = maxB;
  if (t == (int)(B >> 3)) {
    unsigned i = B & 7u;
    unsigned n = bs[i] + h[i];
    sel[0] = B;
    counter[0] = n < (unsigned)kCap ? n : (unsigned)kCap;
  }
}

// Per-bin scatter append: pos = binStart[bin] + binCount[bin]++ (padded).
__device__ __forceinline__ void try_append(float s, unsigned g, unsigned B,
                                           const unsigned* __restrict__ binStart,
                                           unsigned* __restrict__ binCount,
                                           unsigned long long* __restrict__ keys) {
  unsigned bin = (unsigned)score_bin(s);
  if (bin >= B) {
    unsigned pos = binStart[bin] + atomicAdd(&binCount[bin << 4], 1u);
    if (pos < (unsigned)kCap) {
      // key: high 32 = score bits (scores >= 0 so monotonic), low 32 = ~index
      // -> rank by key DESC gives (score desc, index asc) == lax.top_k order.
      keys[pos] = ((unsigned long long)__float_as_uint(s) << 32) |
                  (unsigned long long)(0xFFFFFFFFu - g);
    }
  }
}

// Sidecar path: coalesced float4 read of dense scores[] (4 anchors/lane).
__global__ void compact_s_kernel(const float4* __restrict__ scores4,
                                 const unsigned* __restrict__ sel,
                                 const unsigned* __restrict__ binStart,
                                 unsigned* __restrict__ binCount,
                                 unsigned long long* __restrict__ keys) {
  int t = blockIdx.x * blockDim.x + threadIdx.x;
  if (t >= kNTot / 4) return;
  float4 v = scores4[t];
  unsigned g0 = (unsigned)t * 4;
  unsigned B = sel[0];
  try_append(v.x, g0 + 0, B, binStart, binCount, keys);
  try_append(v.y, g0 + 1, B, binStart, binCount, keys);
  try_append(v.z, g0 + 2, B, binStart, binCount, keys);
  try_append(v.w, g0 + 3, B, binStart, binCount, keys);
}

// Fallback path (ws too small for sidecar): strided x read.
__global__ void compact_x_kernel(const float* __restrict__ x1, const float* __restrict__ x2,
                                 const float* __restrict__ x3, const float* __restrict__ x4,
                                 const unsigned* __restrict__ sel,
                                 const unsigned* __restrict__ binStart,
                                 unsigned* __restrict__ binCount,
                                 unsigned long long* __restrict__ keys) {
  int t = blockIdx.x * blockDim.x + threadIdx.x;
  if (t >= kNTot / 4) return;
  unsigned g0 = (unsigned)t * 4;
  LevelPick lp = pick_level(g0, x1, x2, x3, x4);
  float s[4];
  load_scores4(lp.x, lp.local, s);
  unsigned B = sel[0];
  #pragma unroll
  for (int i = 0; i < 4; ++i) try_append(s[i], g0 + i, B, binStart, binCount, keys);
}

// Exact sort by rank-counting (keys distinct, order-independent) with fused
// scatter: rankArr[i] accumulates partial+(1<<20); the contributor whose add
// completes the count (single-location RMW => totally ordered) writes
// sorted[rank] = keys[i].
__global__ void rank_kernel(const unsigned long long* __restrict__ keys,
                            const unsigned* __restrict__ counter,
                            unsigned* __restrict__ rankArr,
                            unsigned long long* __restrict__ sorted) {
  __shared__ unsigned long long lk[kJChunk];
  int n = (int)*counter;
  int itile = blockIdx.x / (kCap / kJChunk);
  int jc = blockIdx.x % (kCap / kJChunk);
  int i0 = itile * kITile;
  int j0 = jc * kJChunk;
  if (i0 >= n || j0 >= n) return;
  const unsigned nJC = (unsigned)((n + kJChunk - 1) / kJChunk);
  for (int j = threadIdx.x; j < kJChunk; j += kITile) {
    int jj = j0 + j;
    lk[j] = (jj < n) ? keys[jj] : 0ull;  // zero-pad: 0 never counts as greater
  }
  __syncthreads();
  int i = i0 + threadIdx.x;
  unsigned long long ki = (i < n) ? keys[i] : ~0ull;
  int r0 = 0, r1 = 0, r2 = 0, r3 = 0;
  const ulonglong2* p2 = (const ulonglong2*)lk;  // 1024 entries
  #pragma unroll 4
  for (int j = 0; j < kJChunk / 8; ++j) {        // 256 iters, 4 streams
    ulonglong2 a = p2[j];
    ulonglong2 b = p2[256 + j];
    ulonglong2 c = p2[512 + j];
    ulonglong2 d = p2[768 + j];
    r0 += (int)(a.x > ki) + (int)(a.y > ki);
    r1 += (int)(b.x > ki) + (int)(b.y > ki);
    r2 += (int)(c.x > ki) + (int)(c.y > ki);
    r3 += (int)(d.x > ki) + (int)(d.y > ki);
  }
  if (i < n) {
    unsigned add = (unsigned)(r0 + r1 + r2 + r3) + kDoneInc;
    unsigned newv = atomicAdd(&rankArr[i], add) + add;
    if ((newv >> 20) == nJC) {
      unsigned r = newv & (kDoneInc - 1u);
      if (r < (unsigned)kNPad) sorted[r] = ki;
    }
  }
}

__device__ __forceinline__ void decode_box(unsigned g,
                                           const float* __restrict__ x1, const float* __restrict__ x2,
                                           const float* __restrict__ x3, const float* __restrict__ x4,
                                           const float* __restrict__ a1, const float* __restrict__ a2,
                                           const float* __restrict__ a3, const float* __restrict__ a4,
                                           float4* box) {
  const float* x;
  const float* anc;
  unsigned local;
  if (g < (unsigned)kB1)      { x = x1; anc = a1; local = g; }
  else if (g < (unsigned)kB2) { x = x2; anc = a2; local = g - kB1; }
  else if (g < (unsigned)kB3) { x = x3; anc = a3; local = g - kB2; }
  else                        { x = x4; anc = a4; local = g - kB3; }
  const float* xe = x + (size_t)local * 6;
  float dy = xe[2], dx = xe[3], dh = xe[4], dwv = xe[5];
  const float* ae = anc + (size_t)local * 4;
  float ay1 = ae[0], ax1 = ae[1], ay2 = ae[2], ax2 = ae[3];
  float ah = ay2 - ay1;
  float aw = ax2 - ax1;
  float acy = ay1 + 0.5f * ah;
  float acx = ax1 + 0.5f * aw;
  float cy = acy + dy * ah;
  float cx = acx + dx * aw;
  float bh = ah * expf(dh);
  float bw = aw * expf(dwv);
  box->x = fminf(fmaxf(cy - 0.5f * bh, 0.0f), 2048.0f);
  box->y = fminf(fmaxf(cx - 0.5f * bw, 0.0f), 2048.0f);
  box->z = fminf(fmaxf(cy + 0.5f * bh, 0.0f), 2048.0f);
  box->w = fminf(fmaxf(cx + 0.5f * bw, 0.0f), 2048.0f);
}

// decode rank r's box (zero beyond top-k / count), emit supinit words.
__global__ void decode_kernel(const unsigned long long* __restrict__ sorted,
                              const unsigned* __restrict__ counter,
                              const float* __restrict__ x1, const float* __restrict__ x2,
                              const float* __restrict__ x3, const float* __restrict__ x4,
                              const float* __restrict__ a1, const float* __restrict__ a2,
                              const float* __restrict__ a3, const float* __restrict__ a4,
                              float4* __restrict__ boxes,
                              unsigned long long* __restrict__ supinit) {
  int r = blockIdx.x * 256 + threadIdx.x;
  int n = min((int)*counter, kTopK);
  unsigned long long key = (r < n) ? sorted[r] : 0ull;
  float4 box = make_float4(0.f, 0.f, 0.f, 0.f);
  float sc = 0.f;
  if (key != 0ull) {
    sc = __uint_as_float((unsigned)(key >> 32));
    unsigned g = 0xFFFFFFFFu - (unsigned)(key & 0xFFFFFFFFull);
    if (g < (unsigned)kNTot) decode_box(g, x1, x2, x3, x4, a1, a2, a3, a4, &box);
  }
  boxes[r] = box;
  unsigned long long dead = __ballot(!(sc >= 0.5f));
  if ((threadIdx.x & 63) == 0) supinit[r >> 6] = dead;
}

// One wave per (row, 4-word column group); upper triangle only. bi loaded
// once per wave.
__global__ void iou_kernel(const float4* __restrict__ boxes,
                           unsigned long long* __restrict__ rows) {
  int wave = (blockIdx.x * blockDim.x + threadIdx.x) >> 6;
  int lane = threadIdx.x & 63;
  if (wave >= kTopK * 16) return;
  int row = wave >> 4;
  int wg = wave & 15;
  int W0 = row >> 6;
  if (wg * 4 + 3 < W0) return;  // whole group lower-triangle
  float4 bi = boxes[row];
  float ar1 = (bi.z - bi.x) * (bi.w - bi.y);
  #pragma unroll
  for (int w = 0; w < 4; ++w) {
    int wc = wg * 4 + w;
    if (wc < W0) continue;
    float4 bj = boxes[wc * 64 + lane];
    float yy1 = fmaxf(bi.x, bj.x);
    float xx1 = fmaxf(bi.y, bj.y);
    float yy2 = fminf(bi.z, bj.z);
    float xx2 = fminf(bi.w, bj.w);
    float inter = fmaxf(yy2 - yy1, 0.0f) * fmaxf(xx2 - xx1, 0.0f);
    float ar2 = (bj.z - bj.x) * (bj.w - bj.y);
    float iou = inter / (ar1 + ar2 - inter + 1e-9f);
    unsigned long long m = __ballot(iou > 0.5f);
    if (lane == 0) rows[(size_t)row * 64 + wc] = m;
  }
}

__device__ __forceinline__ void glds16(const void* g, void* l) {
  __builtin_amdgcn_global_load_lds(
      (const __attribute__((address_space(1))) unsigned int*)g,
      (__attribute__((address_space(3))) unsigned int*)l, 16, 0, 0);
}

// Stage one chunk into LDS; ninst x glds16 (ninst=16 for the final partial
// chunk: ranks 4000.. have no rows; 16 insts = rows 3968..3999 exactly).
__device__ __forceinline__ void stage_chunk(const unsigned long long* rows, int chunk,
                                            unsigned long long* dst, int lane, int ninst) {
  const char* src = (const char*)(rows + (size_t)chunk * kChunk * 64);
  char* d = (char*)dst;
  for (int i = 0; i < ninst; ++i) {
    glds16(src + i * 1024 + lane * 16, d + i * 1024);
  }
}

// 8 waves, 1 CU. Wave 0 = scan; waves 1..7 = prefetchers, DECOUPLED 1-deep:
//   {wait slot free -> stage -> vmcnt(0) -> EXTRACT diag slice -> lgkmcnt(0)
//    -> ready[c]}.
// The diag extraction (buf[lane*64+c], 64-way bank conflict) runs on the
// slack-rich prefetcher. Scan per chunk: dreg = diagSlice[slot][lane]
// (conflict-free); per pick the mask update is shfl(dreg, i) only; the
// full-row fold into sup stays off the mask path.
__global__ __launch_bounds__(512, 1) void greedy_kernel(
    const float4* __restrict__ boxes,
    const unsigned long long* __restrict__ supinit,
    const unsigned long long* __restrict__ rows,
    float* __restrict__ out) {
  __shared__ unsigned long long slots[kNSlots][kChunk * 64];  // 4 x 32KB
  __shared__ unsigned long long diagSlice[kNSlots][64];       // 2KB
  __shared__ unsigned readyF[kNChunks];
  __shared__ unsigned consumedF;
  __shared__ unsigned doneF;
  __shared__ int picksLds[kNRois];
  __shared__ int countSh;

  volatile unsigned* vready = readyF;
  volatile unsigned* vconsumed = &consumedF;
  volatile unsigned* vdone = &doneF;

  const int tid = threadIdx.x;
  const int wid = tid >> 6;
  const int lane = tid & 63;

  for (int i = tid; i < kNChunks; i += 512) readyF[i] = 0;
  if (tid == 0) { consumedF = 0; doneF = 0; countSh = 0; }
  __syncthreads();

  if (wid > 0) {
    // ---- prefetcher wave: chunks c == wid-1 (mod 7), 1-deep decoupled ----
    for (int c = wid - 1; c < kNChunks; c += kNPref) {
      while (!*vdone && (int)*vconsumed < c - (kNSlots - 1))
        __builtin_amdgcn_s_sleep(1);
      if (*vdone) break;
      const int slot = c & (kNSlots - 1);
      const int ni = (c == kNChunks - 1) ? 16 : 32;
      stage_chunk(rows, c, &slots[slot][0], lane, ni);
      asm volatile("s_waitcnt vmcnt(0)" ::: "memory");
      __builtin_amdgcn_sched_barrier(0);
      // extract diag slice: rows[base+lane] word c (conflicted; off scan path)
      diagSlice[slot][lane] = slots[slot][lane * 64 + c];
      asm volatile("s_waitcnt lgkmcnt(0)" ::: "memory");
      __builtin_amdgcn_sched_barrier(0);
      if (lane == 0) vready[c] = 1;
    }
  } else {
    // ---- scan wave: chunk c covers sup word c exactly ----
    unsigned long long sup = supinit[lane];
    int count = 0;
    for (int c = 0; c < kNChunks; ++c) {
      while (vready[c] == 0) __builtin_amdgcn_s_sleep(1);
      asm volatile("" ::: "memory");  // data reads stay below the spin
      const int slot = c & (kNSlots - 1);
      const unsigned long long* buf = &slots[slot][0];
      const int base = c * kChunk;
      unsigned long long dreg = diagSlice[slot][lane];  // conflict-free
      unsigned long long cw = __shfl(sup, c);
      unsigned long long mask = ~cw;  // alive bits in this word
      while (mask != 0ull && count < kNRois) {
        const int i = __builtin_ctzll(mask);
        const int r = base + i;
        unsigned long long row = buf[i * 64 + lane];  // full row (for sup)
        if (lane == 0) picksLds[count] = r;
        ++count;
        sup |= row;
        if (lane == c) sup |= 1ull << i;  // self (deg. zero-area boxes)
        mask &= ~(__shfl(dreg, i) | (1ull << i));  // shfl-only mask path
      }
      if (lane == 0) *vconsumed = (unsigned)(c + 1);
      if (count == kNRois) break;
      if (__ballot(lane > c && (~sup) != 0ull) == 0ull) break;  // none ahead
    }
    if (lane == 0) { countSh = count; *vdone = 1u; }
  }
  __syncthreads();
  const int cnt = countSh;
  for (int p = tid; p < kNRois; p += 512) {
    float4 bx = make_float4(0.f, 0.f, 0.f, 0.f);
    if (p < cnt) bx = boxes[picksLds[p]];
    ((float4*)out)[p] = bx;  // zero-pads the tail
  }
}

}  // namespace

extern "C" void kernel_launch(void* const* d_in, const int* in_sizes, int n_in,
                              void* d_out, int out_size, void* d_ws, size_t ws_size,
                              hipStream_t stream) {
  const float* x1 = (const float*)d_in[0];
  const float* a1 = (const float*)d_in[1];
  const float* x2 = (const float*)d_in[2];
  const float* a2 = (const float*)d_in[3];
  const float* x3 = (const float*)d_in[4];
  const float* a3 = (const float*)d_in[5];
  const float* x4 = (const float*)d_in[6];
  const float* a4 = (const float*)d_in[7];

  char* ws = (char*)d_ws;
  size_t off = 0;
  unsigned* part = (unsigned*)(ws + off);       off += (size_t)kNParts * kNBins * 4;
  unsigned* hist = (unsigned*)(ws + off);       off += kNBins * 4;
  unsigned* counter = (unsigned*)(ws + off);    off += 4;
  unsigned* sel = (unsigned*)(ws + off);        off += 4;
  unsigned* rankArr = (unsigned*)(ws + off);    off += (size_t)kCap * 4;
  unsigned* binCount = (unsigned*)(ws + off);   off += (size_t)kNBins * kBCS * 4;
  unsigned* binStart = (unsigned*)(ws + off);   off += (size_t)kNBins * 4;
  unsigned long long* supinit = (unsigned long long*)(ws + off);  off += 512 + 8;
  unsigned long long* sorted = (unsigned long long*)(ws + off);   off += (size_t)kNPad * 8;
  unsigned long long* keys = (unsigned long long*)(ws + off);     off += (size_t)kCap * 8;
  float4* boxes = (float4*)(ws + off);          off += (size_t)kNPad * 16;
  unsigned long long* rows = (unsigned long long*)(ws + off);     off += (size_t)kTopK * 64 * 8;
  const bool sidecar = ws_size >= off + (size_t)kNTot * 4;
  float* scores = sidecar ? (float*)(ws + off) : nullptr;
  float* out = (float*)d_out;

  hist_kernel<<<kNParts, 1024, 0, stream>>>(
      (const float4*)x1, (const float4*)x2, (const float4*)x3, (const float4*)x4,
      part, scores);
  reduce_kernel<<<kNBins / 256, 256, 0, stream>>>(part, hist, rankArr, binCount);
  select_kernel<<<1, 1024, 0, stream>>>(hist, sel, counter, binStart);
  int blocks4 = (kNTot / 4 + 255) / 256;  // 3060
  if (sidecar) {
    compact_s_kernel<<<blocks4, 256, 0, stream>>>(
        (const float4*)scores, sel, binStart, binCount, keys);
  } else {
    compact_x_kernel<<<blocks4, 256, 0, stream>>>(
        x1, x2, x3, x4, sel, binStart, binCount, keys);
  }
  rank_kernel<<<(kCap / kITile) * (kCap / kJChunk), kITile, 0, stream>>>(
      keys, counter, rankArr, sorted);
  decode_kernel<<<kNPad / 256, 256, 0, stream>>>(
      sorted, counter, x1, x2, x3, x4, a1, a2, a3, a4, boxes, supinit);
  iou_kernel<<<(kTopK * 16 * 64) / 256, 256, 0, stream>>>(boxes, rows);
  greedy_kernel<<<1, 512, 0, stream>>>(boxes, supinit, rows, out);
}

// Round 20
// 118.090 us; speedup vs baseline: 1.0378x; 1.0378x over previous
//
#include <hip/hip_runtime.h>

// ---------------------------------------------------------------------------
// PyramidNSMLayer: 4-level anchor decode + top-4000 selection + greedy NMS.
// == R18 (best measured: 118.6us) ==
//
// Pipeline (all on `stream`, graph-capturable, deterministic):
//   1. hist_kernel:    coalesced float4 stream, per-LEVEL block partition,
//                      period-3 score extract, LDS 8192-bin hist -> partials,
//                      dense scores[] sidecar (if ws allows)
//   2. reduce_kernel:  column-sum partials -> hist; zeroes rankArr/binCount
//   3. select_kernel:  parallel suffix-scan -> binStart[], B = LARGEST bin
//                      with suffix >= 4000
//   4. compact:        per-bin scatter, binCount 1 cacheline/bin
//   5. rank_kernel:    rank-by-counting exact sort (keys distinct), 2D-split;
//                      fused scatter (contribution count in bit 20; last
//                      contributor writes sorted[rank])
//   6. decode_kernel:  decode top-4000 ranks into boxes + supinit bitmask
//   7. iou_kernel:     upper-triangle 4000 x 4096 bitmask, 4 col-words/wave
//   8. greedy_kernel:  8 waves / 1 CU decoupled ring; scan's per-pick mask
//                      update uses a parallel uniform-address LDS read of the
//                      row's word c (issued alongside the full-row read: ONE
//                      shared LDS latency per pick). NOTE (R19 lesson):
//                      __shfl is ds_bpermute = lgkmcnt-counted, so no LDS/
//                      shfl scheme can take the row read off the mask path.
// ---------------------------------------------------------------------------

namespace {

constexpr int kNTot = 3133440;   // total anchors across levels
constexpr int kB1 = 2359296;     // 512*512*9
constexpr int kB2 = 2949120;     // + 256*256*9
constexpr int kB3 = 3096576;     // + 128*128*9
constexpr int kNBins = 8192;
constexpr int kNParts = 256;     // histogram partial blocks
constexpr int kCap = 8192;       // candidate buffer capacity
constexpr int kTopK = 4000;
constexpr int kNPad = 4096;      // padded candidate count for 64-bit words
constexpr int kNRois = 300;
constexpr int kChunk = 64;       // greedy scan chunk (ranks per slot) == 1 word
constexpr int kNChunks = (kTopK + kChunk - 1) / kChunk;  // 63
constexpr int kNSlots = 4;       // LDS ring slots (32KB each)
constexpr int kNPref = 7;        // prefetcher waves (1-deep each, decoupled)
constexpr int kJChunk = 2048;    // rank j-chunk (16KB LDS)
constexpr int kITile = 256;      // rank i-tile (threads per block)
constexpr int kBCS = 16;         // binCount stride (u32) = 1 cacheline/bin
constexpr unsigned kDoneInc = 1u << 20;  // rank contribution-count increment

// float4-stream geometry (x inputs, layout (h,w,9,6) == linear float idx 6a)
constexpr int kF4L[4] = {3538944, 884736, 221184, 55296};  // per-level f4 count
constexpr int kLvlB0[5] = {0, 193, 241, 253, 256};         // block partition
constexpr int kLvlAB[4] = {0, kB1, kB2, kB3};

struct LevelPick { const float* x; unsigned local; };

__device__ __forceinline__ LevelPick pick_level(unsigned g, const float* x1, const float* x2,
                                                const float* x3, const float* x4) {
  LevelPick p;
  if (g < (unsigned)kB1)      { p.x = x1; p.local = g; }
  else if (g < (unsigned)kB2) { p.x = x2; p.local = g - kB1; }
  else if (g < (unsigned)kB3) { p.x = x3; p.local = g - kB2; }
  else                        { p.x = x4; p.local = g - kB3; }
  return p;
}

__device__ __forceinline__ int score_bin(float s) {
  int b = (int)(s * (float)kNBins);
  return min(max(b, 0), kNBins - 1);
}

// Strided fallback: 4 consecutive anchors' scores via aligned float4s.
__device__ __forceinline__ void load_scores4(const float* x, unsigned local0, float s[4]) {
  const float4* p = (const float4*)(x + (size_t)local0 * 6);
  float4 q0 = p[0], q1 = p[1], q3 = p[3], q4 = p[4];
  s[0] = q0.x; s[1] = q1.z; s[2] = q3.x; s[3] = q4.z;
}

// Coalesced stream pass, blocks statically partitioned across levels.
__global__ __launch_bounds__(1024) void hist_kernel(
    const float4* __restrict__ x1, const float4* __restrict__ x2,
    const float4* __restrict__ x3, const float4* __restrict__ x4,
    unsigned* __restrict__ part, float* __restrict__ scores) {
  __shared__ unsigned h[kNBins];
  for (int i = threadIdx.x; i < kNBins; i += 1024) h[i] = 0;
  __syncthreads();
  const int bid = blockIdx.x;
  int lvl = (bid < kLvlB0[1]) ? 0 : (bid < kLvlB0[2]) ? 1 : (bid < kLvlB0[3]) ? 2 : 3;
  const float4* x = (lvl == 0) ? x1 : (lvl == 1) ? x2 : (lvl == 2) ? x3 : x4;
  const int nf4 = kF4L[lvl];
  const int abase = kLvlAB[lvl];
  const int bloc = bid - kLvlB0[lvl];
  const int nblk = kLvlB0[lvl + 1] - kLvlB0[lvl];
  for (int q = bloc * 1024 + threadIdx.x; q < nf4; q += nblk * 1024) {
    float4 v = x[q];
    int qd = q / 3;
    int r = q - qd * 3;
    if (r != 2) {
      float s = (r == 0) ? v.x : v.z;
      atomicAdd(&h[score_bin(s)], 1u);
      if (scores) scores[abase + 2 * qd + r] = s;
    }
  }
  __syncthreads();
  for (int i = threadIdx.x; i < kNBins; i += 1024)
    part[blockIdx.x * kNBins + i] = h[i];
}

// hist[b] = sum over partials; also zeroes rankArr and binCount (replaces
// the memset dispatch; runs before their users in the stream).
__global__ void reduce_kernel(const unsigned* __restrict__ part, unsigned* __restrict__ hist,
                              unsigned* __restrict__ rankArr, unsigned* __restrict__ binCount) {
  int b = blockIdx.x * 256 + threadIdx.x;
  unsigned t0 = 0, t1 = 0, t2 = 0, t3 = 0;
  for (int p = 0; p < kNParts; p += 4) {
    t0 += part[(size_t)(p + 0) * kNBins + b];
    t1 += part[(size_t)(p + 1) * kNBins + b];
    t2 += part[(size_t)(p + 2) * kNBins + b];
    t3 += part[(size_t)(p + 3) * kNBins + b];
  }
  hist[b] = t0 + t1 + t2 + t3;
  rankArr[b] = 0;
  #pragma unroll
  for (int k = 0; k < kBCS; ++k) binCount[(size_t)b * kBCS + k] = 0;
}

// 1 block, 1024 threads. Parallel suffix scan of hist -> binStart[b] =
// #candidates in bins > b. B = LARGEST bin with suffix >= topk (atomicMax).
__global__ __launch_bounds__(1024) void select_kernel(
    const unsigned* __restrict__ hist, unsigned* __restrict__ sel,
    unsigned* __restrict__ counter, unsigned* __restrict__ binStart) {
  __shared__ unsigned wtot[16];
  __shared__ unsigned maxB;
  const int t = threadIdx.x;
  const int lane = t & 63;
  const int wv = t >> 6;
  if (t == 0) maxB = 0u;
  unsigned h[8];
  unsigned s = 0;
  #pragma unroll
  for (int i = 0; i < 8; ++i) { h[i] = hist[t * 8 + i]; s += h[i]; }
  unsigned p = s;
  #pragma unroll
  for (int off = 1; off < 64; off <<= 1) {
    unsigned n = __shfl_up(p, off);
    if (lane >= off) p += n;
  }
  if (lane == 63) wtot[wv] = p;
  __syncthreads();
  if (wv == 0 && lane < 16) {
    unsigned wp = wtot[lane];
    #pragma unroll
    for (int off = 1; off < 16; off <<= 1) {
      unsigned n = __shfl_up(wp, off);
      if (lane >= off) wp += n;
    }
    wtot[lane] = wp;  // inclusive across waves
  }
  __syncthreads();
  const unsigned total = wtot[15];
  const unsigned Pincl = p + (wv > 0 ? wtot[wv - 1] : 0u);
  const unsigned T = total - Pincl;  // sum over threads above t
  unsigned bs[8];
  bs[7] = T;
  #pragma unroll
  for (int i = 6; i >= 0; --i) bs[i] = bs[i + 1] + h[i + 1];
  #pragma unroll
  for (int i = 0; i < 8; ++i) binStart[t * 8 + i] = bs[i];
  unsigned cand = 0;
  #pragma unroll
  for (int i = 0; i < 8; ++i)            // ascending: ends at LARGEST
    if (bs[i] + h[i] >= (unsigned)kTopK) cand = (unsigned)(t * 8 + i);
  atomicMax(&maxB, cand);
  __syncthreads();
  const unsigned B = maxB;
  if (t == (int)(B >> 3)) {
    unsigned i = B & 7u;
    unsigned n = bs[i] + h[i];
    sel[0] = B;
    counter[0] = n < (unsigned)kCap ? n : (unsigned)kCap;
  }
}

// Per-bin scatter append: pos = binStart[bin] + binCount[bin]++ (padded).
__device__ __forceinline__ void try_append(float s, unsigned g, unsigned B,
                                           const unsigned* __restrict__ binStart,
                                           unsigned* __restrict__ binCount,
                                           unsigned long long* __restrict__ keys) {
  unsigned bin = (unsigned)score_bin(s);
  if (bin >= B) {
    unsigned pos = binStart[bin] + atomicAdd(&binCount[bin << 4], 1u);
    if (pos < (unsigned)kCap) {
      // key: high 32 = score bits (scores >= 0 so monotonic), low 32 = ~index
      // -> rank by key DESC gives (score desc, index asc) == lax.top_k order.
      keys[pos] = ((unsigned long long)__float_as_uint(s) << 32) |
                  (unsigned long long)(0xFFFFFFFFu - g);
    }
  }
}

// Sidecar path: coalesced float4 read of dense scores[] (4 anchors/lane).
__global__ void compact_s_kernel(const float4* __restrict__ scores4,
                                 const unsigned* __restrict__ sel,
                                 const unsigned* __restrict__ binStart,
                                 unsigned* __restrict__ binCount,
                                 unsigned long long* __restrict__ keys) {
  int t = blockIdx.x * blockDim.x + threadIdx.x;
  if (t >= kNTot / 4) return;
  float4 v = scores4[t];
  unsigned g0 = (unsigned)t * 4;
  unsigned B = sel[0];
  try_append(v.x, g0 + 0, B, binStart, binCount, keys);
  try_append(v.y, g0 + 1, B, binStart, binCount, keys);
  try_append(v.z, g0 + 2, B, binStart, binCount, keys);
  try_append(v.w, g0 + 3, B, binStart, binCount, keys);
}

// Fallback path (ws too small for sidecar): strided x read.
__global__ void compact_x_kernel(const float* __restrict__ x1, const float* __restrict__ x2,
                                 const float* __restrict__ x3, const float* __restrict__ x4,
                                 const unsigned* __restrict__ sel,
                                 const unsigned* __restrict__ binStart,
                                 unsigned* __restrict__ binCount,
                                 unsigned long long* __restrict__ keys) {
  int t = blockIdx.x * blockDim.x + threadIdx.x;
  if (t >= kNTot / 4) return;
  unsigned g0 = (unsigned)t * 4;
  LevelPick lp = pick_level(g0, x1, x2, x3, x4);
  float s[4];
  load_scores4(lp.x, lp.local, s);
  unsigned B = sel[0];
  #pragma unroll
  for (int i = 0; i < 4; ++i) try_append(s[i], g0 + i, B, binStart, binCount, keys);
}

// Exact sort by rank-counting (keys distinct, order-independent) with fused
// scatter: rankArr[i] accumulates partial+(1<<20); the contributor whose add
// completes the count (single-location RMW => totally ordered) writes
// sorted[rank] = keys[i].
__global__ void rank_kernel(const unsigned long long* __restrict__ keys,
                            const unsigned* __restrict__ counter,
                            unsigned* __restrict__ rankArr,
                            unsigned long long* __restrict__ sorted) {
  __shared__ unsigned long long lk[kJChunk];
  int n = (int)*counter;
  int itile = blockIdx.x / (kCap / kJChunk);
  int jc = blockIdx.x % (kCap / kJChunk);
  int i0 = itile * kITile;
  int j0 = jc * kJChunk;
  if (i0 >= n || j0 >= n) return;
  const unsigned nJC = (unsigned)((n + kJChunk - 1) / kJChunk);
  for (int j = threadIdx.x; j < kJChunk; j += kITile) {
    int jj = j0 + j;
    lk[j] = (jj < n) ? keys[jj] : 0ull;  // zero-pad: 0 never counts as greater
  }
  __syncthreads();
  int i = i0 + threadIdx.x;
  unsigned long long ki = (i < n) ? keys[i] : ~0ull;
  int r0 = 0, r1 = 0, r2 = 0, r3 = 0;
  const ulonglong2* p2 = (const ulonglong2*)lk;  // 1024 entries
  #pragma unroll 4
  for (int j = 0; j < kJChunk / 8; ++j) {        // 256 iters, 4 streams
    ulonglong2 a = p2[j];
    ulonglong2 b = p2[256 + j];
    ulonglong2 c = p2[512 + j];
    ulonglong2 d = p2[768 + j];
    r0 += (int)(a.x > ki) + (int)(a.y > ki);
    r1 += (int)(b.x > ki) + (int)(b.y > ki);
    r2 += (int)(c.x > ki) + (int)(c.y > ki);
    r3 += (int)(d.x > ki) + (int)(d.y > ki);
  }
  if (i < n) {
    unsigned add = (unsigned)(r0 + r1 + r2 + r3) + kDoneInc;
    unsigned newv = atomicAdd(&rankArr[i], add) + add;
    if ((newv >> 20) == nJC) {
      unsigned r = newv & (kDoneInc - 1u);
      if (r < (unsigned)kNPad) sorted[r] = ki;
    }
  }
}

__device__ __forceinline__ void decode_box(unsigned g,
                                           const float* __restrict__ x1, const float* __restrict__ x2,
                                           const float* __restrict__ x3, const float* __restrict__ x4,
                                           const float* __restrict__ a1, const float* __restrict__ a2,
                                           const float* __restrict__ a3, const float* __restrict__ a4,
                                           float4* box) {
  const float* x;
  const float* anc;
  unsigned local;
  if (g < (unsigned)kB1)      { x = x1; anc = a1; local = g; }
  else if (g < (unsigned)kB2) { x = x2; anc = a2; local = g - kB1; }
  else if (g < (unsigned)kB3) { x = x3; anc = a3; local = g - kB2; }
  else                        { x = x4; anc = a4; local = g - kB3; }
  const float* xe = x + (size_t)local * 6;
  float dy = xe[2], dx = xe[3], dh = xe[4], dwv = xe[5];
  const float* ae = anc + (size_t)local * 4;
  float ay1 = ae[0], ax1 = ae[1], ay2 = ae[2], ax2 = ae[3];
  float ah = ay2 - ay1;
  float aw = ax2 - ax1;
  float acy = ay1 + 0.5f * ah;
  float acx = ax1 + 0.5f * aw;
  float cy = acy + dy * ah;
  float cx = acx + dx * aw;
  float bh = ah * expf(dh);
  float bw = aw * expf(dwv);
  box->x = fminf(fmaxf(cy - 0.5f * bh, 0.0f), 2048.0f);
  box->y = fminf(fmaxf(cx - 0.5f * bw, 0.0f), 2048.0f);
  box->z = fminf(fmaxf(cy + 0.5f * bh, 0.0f), 2048.0f);
  box->w = fminf(fmaxf(cx + 0.5f * bw, 0.0f), 2048.0f);
}

// decode rank r's box (zero beyond top-k / count), emit supinit words.
__global__ void decode_kernel(const unsigned long long* __restrict__ sorted,
                              const unsigned* __restrict__ counter,
                              const float* __restrict__ x1, const float* __restrict__ x2,
                              const float* __restrict__ x3, const float* __restrict__ x4,
                              const float* __restrict__ a1, const float* __restrict__ a2,
                              const float* __restrict__ a3, const float* __restrict__ a4,
                              float4* __restrict__ boxes,
                              unsigned long long* __restrict__ supinit) {
  int r = blockIdx.x * 256 + threadIdx.x;
  int n = min((int)*counter, kTopK);
  unsigned long long key = (r < n) ? sorted[r] : 0ull;
  float4 box = make_float4(0.f, 0.f, 0.f, 0.f);
  float sc = 0.f;
  if (key != 0ull) {
    sc = __uint_as_float((unsigned)(key >> 32));
    unsigned g = 0xFFFFFFFFu - (unsigned)(key & 0xFFFFFFFFull);
    if (g < (unsigned)kNTot) decode_box(g, x1, x2, x3, x4, a1, a2, a3, a4, &box);
  }
  boxes[r] = box;
  unsigned long long dead = __ballot(!(sc >= 0.5f));
  if ((threadIdx.x & 63) == 0) supinit[r >> 6] = dead;
}

// One wave per (row, 4-word column group); upper triangle only. bi loaded
// once per wave.
__global__ void iou_kernel(const float4* __restrict__ boxes,
                           unsigned long long* __restrict__ rows) {
  int wave = (blockIdx.x * blockDim.x + threadIdx.x) >> 6;
  int lane = threadIdx.x & 63;
  if (wave >= kTopK * 16) return;
  int row = wave >> 4;
  int wg = wave & 15;
  int W0 = row >> 6;
  if (wg * 4 + 3 < W0) return;  // whole group lower-triangle
  float4 bi = boxes[row];
  float ar1 = (bi.z - bi.x) * (bi.w - bi.y);
  #pragma unroll
  for (int w = 0; w < 4; ++w) {
    int wc = wg * 4 + w;
    if (wc < W0) continue;
    float4 bj = boxes[wc * 64 + lane];
    float yy1 = fmaxf(bi.x, bj.x);
    float xx1 = fmaxf(bi.y, bj.y);
    float yy2 = fminf(bi.z, bj.z);
    float xx2 = fminf(bi.w, bj.w);
    float inter = fmaxf(yy2 - yy1, 0.0f) * fmaxf(xx2 - xx1, 0.0f);
    float ar2 = (bj.z - bj.x) * (bj.w - bj.y);
    float iou = inter / (ar1 + ar2 - inter + 1e-9f);
    unsigned long long m = __ballot(iou > 0.5f);
    if (lane == 0) rows[(size_t)row * 64 + wc] = m;
  }
}

__device__ __forceinline__ void glds16(const void* g, void* l) {
  __builtin_amdgcn_global_load_lds(
      (const __attribute__((address_space(1))) unsigned int*)g,
      (__attribute__((address_space(3))) unsigned int*)l, 16, 0, 0);
}

// Stage one chunk into LDS; ninst x glds16 (ninst=16 for the final partial
// chunk: ranks 4000.. have no rows; 16 insts = rows 3968..3999 exactly).
__device__ __forceinline__ void stage_chunk(const unsigned long long* rows, int chunk,
                                            unsigned long long* dst, int lane, int ninst) {
  const char* src = (const char*)(rows + (size_t)chunk * kChunk * 64);
  char* d = (char*)dst;
  for (int i = 0; i < ninst; ++i) {
    glds16(src + i * 1024 + lane * 16, d + i * 1024);
  }
}

// 8 waves, 1 CU. Wave 0 = scan; waves 1..7 = prefetchers, DECOUPLED 1-deep
// (R16-proven): {wait slot free -> stage -> vmcnt(0) -> ready[c]}.
// Scan wave = skip-scan; mask update reads the row's word c via a SECOND,
// uniform-address LDS read (broadcast, issued in parallel with the full-row
// read) -- one shared LDS latency per pick.
__global__ __launch_bounds__(512, 1) void greedy_kernel(
    const float4* __restrict__ boxes,
    const unsigned long long* __restrict__ supinit,
    const unsigned long long* __restrict__ rows,
    float* __restrict__ out) {
  __shared__ unsigned long long slots[kNSlots][kChunk * 64];  // 4 x 32KB
  __shared__ unsigned readyF[kNChunks];
  __shared__ unsigned consumedF;
  __shared__ unsigned doneF;
  __shared__ int picksLds[kNRois];
  __shared__ int countSh;

  volatile unsigned* vready = readyF;
  volatile unsigned* vconsumed = &consumedF;
  volatile unsigned* vdone = &doneF;

  const int tid = threadIdx.x;
  const int wid = tid >> 6;
  const int lane = tid & 63;

  for (int i = tid; i < kNChunks; i += 512) readyF[i] = 0;
  if (tid == 0) { consumedF = 0; doneF = 0; countSh = 0; }
  __syncthreads();

  if (wid > 0) {
    // ---- prefetcher wave: chunks c == wid-1 (mod 7), 1-deep decoupled ----
    for (int c = wid - 1; c < kNChunks; c += kNPref) {
      while (!*vdone && (int)*vconsumed < c - (kNSlots - 1))
        __builtin_amdgcn_s_sleep(1);
      if (*vdone) break;
      const int ni = (c == kNChunks - 1) ? 16 : 32;
      stage_chunk(rows, c, &slots[c & (kNSlots - 1)][0], lane, ni);
      asm volatile("s_waitcnt vmcnt(0)" ::: "memory");
      if (lane == 0) vready[c] = 1;
    }
  } else {
    // ---- scan wave: chunk c covers sup word c exactly ----
    unsigned long long sup = supinit[lane];
    int count = 0;
    for (int c = 0; c < kNChunks; ++c) {
      while (vready[c] == 0) __builtin_amdgcn_s_sleep(1);
      asm volatile("" ::: "memory");  // data reads stay below the spin
      const unsigned long long* buf = &slots[c & (kNSlots - 1)][0];
      const int base = c * kChunk;
      unsigned long long cw = __shfl(sup, c);
      unsigned long long mask = ~cw;  // alive bits in this word
      while (mask != 0ull && count < kNRois) {
        const int i = __builtin_ctzll(mask);
        const int r = base + i;
        unsigned long long row = buf[i * 64 + lane];  // full row (for sup)
        unsigned long long dcw = buf[i * 64 + c];     // word c (broadcast)
        if (lane == 0) picksLds[count] = r;
        ++count;
        sup |= row;
        if (lane == c) sup |= 1ull << i;  // self (deg. zero-area boxes)
        mask &= ~(dcw | (1ull << i));     // waits only on the uniform read
      }
      if (lane == 0) *vconsumed = (unsigned)(c + 1);
      if (count == kNRois) break;
      if (__ballot(lane > c && (~sup) != 0ull) == 0ull) break;  // none ahead
    }
    if (lane == 0) { countSh = count; *vdone = 1u; }
  }
  __syncthreads();
  const int cnt = countSh;
  for (int p = tid; p < kNRois; p += 512) {
    float4 bx = make_float4(0.f, 0.f, 0.f, 0.f);
    if (p < cnt) bx = boxes[picksLds[p]];
    ((float4*)out)[p] = bx;  // zero-pads the tail
  }
}

}  // namespace

extern "C" void kernel_launch(void* const* d_in, const int* in_sizes, int n_in,
                              void* d_out, int out_size, void* d_ws, size_t ws_size,
                              hipStream_t stream) {
  const float* x1 = (const float*)d_in[0];
  const float* a1 = (const float*)d_in[1];
  const float* x2 = (const float*)d_in[2];
  const float* a2 = (const float*)d_in[3];
  const float* x3 = (const float*)d_in[4];
  const float* a3 = (const float*)d_in[5];
  const float* x4 = (const float*)d_in[6];
  const float* a4 = (const float*)d_in[7];

  char* ws = (char*)d_ws;
  size_t off = 0;
  unsigned* part = (unsigned*)(ws + off);       off += (size_t)kNParts * kNBins * 4;
  unsigned* hist = (unsigned*)(ws + off);       off += kNBins * 4;
  unsigned* counter = (unsigned*)(ws + off);    off += 4;
  unsigned* sel = (unsigned*)(ws + off);        off += 4;
  unsigned* rankArr = (unsigned*)(ws + off);    off += (size_t)kCap * 4;
  unsigned* binCount = (unsigned*)(ws + off);   off += (size_t)kNBins * kBCS * 4;
  unsigned* binStart = (unsigned*)(ws + off);   off += (size_t)kNBins * 4;
  unsigned long long* supinit = (unsigned long long*)(ws + off);  off += 512 + 8;
  unsigned long long* sorted = (unsigned long long*)(ws + off);   off += (size_t)kNPad * 8;
  unsigned long long* keys = (unsigned long long*)(ws + off);     off += (size_t)kCap * 8;
  float4* boxes = (float4*)(ws + off);          off += (size_t)kNPad * 16;
  unsigned long long* rows = (unsigned long long*)(ws + off);     off += (size_t)kTopK * 64 * 8;
  const bool sidecar = ws_size >= off + (size_t)kNTot * 4;
  float* scores = sidecar ? (float*)(ws + off) : nullptr;
  float* out = (float*)d_out;

  hist_kernel<<<kNParts, 1024, 0, stream>>>(
      (const float4*)x1, (const float4*)x2, (const float4*)x3, (const float4*)x4,
      part, scores);
  reduce_kernel<<<kNBins / 256, 256, 0, stream>>>(part, hist, rankArr, binCount);
  select_kernel<<<1, 1024, 0, stream>>>(hist, sel, counter, binStart);
  int blocks4 = (kNTot / 4 + 255) / 256;  // 3060
  if (sidecar) {
    compact_s_kernel<<<blocks4, 256, 0, stream>>>(
        (const float4*)scores, sel, binStart, binCount, keys);
  } else {
    compact_x_kernel<<<blocks4, 256, 0, stream>>>(
        x1, x2, x3, x4, sel, binStart, binCount, keys);
  }
  rank_kernel<<<(kCap / kITile) * (kCap / kJChunk), kITile, 0, stream>>>(
      keys, counter, rankArr, sorted);
  decode_kernel<<<kNPad / 256, 256, 0, stream>>>(
      sorted, counter, x1, x2, x3, x4, a1, a2, a3, a4, boxes, supinit);
  iou_kernel<<<(kTopK * 16 * 64) / 256, 256, 0, stream>>>(boxes, rows);
  greedy_kernel<<<1, 512, 0, stream>>>(boxes, supinit, rows, out);
}